// Round 6
// baseline (102.032 us; speedup 1.0000x reference)
//
#include <hip/hip_runtime.h>
#include <hip/hip_cooperative_groups.h>

namespace cg = cooperative_groups;

#define B_DIM 64
#define S_LEN 2048
#define H_DIM 256
#define TWO_PI 6.283185307179586f
#define NBLK 256          // 1 block per CU (cooperative, all co-resident)
#define NTHR 1024         // 16 waves per block
#define WAVES 16
#define ROWS_PER_BLK 512  // each block owns one quarter of one b's rows

typedef float f32x4 __attribute__((ext_vector_type(4)));

// Fused: phase 1 per-block partial sums (S0,C1,S1 over its 512 rows) ->
// grid.sync -> phase 2 (redundant per-block combine of the 4 quarter-partials
// of its b) -> phase 3 (low-pass reconstruct + residual + LayerNorm + store).
// Block blk: b = blk>>2, rows [q*512, q*512+512) with q = blk&3 — the SAME
// rows in phase 1 and phase 3, so the re-read hits L3 (x is 128 MB, L3 256 MB;
// out stores are non-temporal so they don't evict x).
__global__ __launch_bounds__(NTHR) void k_fused(const float* __restrict__ x,
                                                const float* __restrict__ sqrt_beta,
                                                const float* __restrict__ lnw,
                                                const float* __restrict__ lnb,
                                                float* __restrict__ out,
                                                float* __restrict__ ws) {
    const int blk = blockIdx.x;
    const int b = blk >> 2;
    const int q = blk & 3;
    const int tid = threadIdx.x;
    const int lane = tid & 63;
    const int wave = tid >> 6;   // 0..15
    const int h0 = lane * 4;

    const float wfreq = TWO_PI / (float)S_LEN;
    const int t_base = q * ROWS_PER_BLK;
    const float* __restrict__ px = x + ((size_t)b * S_LEN + t_base) * H_DIM + h0;

    // ---- Phase 1: partial reductions over this block's 512 rows ----
    // wave w covers rows r === w (mod 16); 2 independent loads per iteration.
    f32x4 s0v = {0.f, 0.f, 0.f, 0.f};
    f32x4 c1v = {0.f, 0.f, 0.f, 0.f};
    f32x4 s1v = {0.f, 0.f, 0.f, 0.f};
    for (int r = wave; r < ROWS_PER_BLK; r += 2 * WAVES) {
        const f32x4 v0 = *reinterpret_cast<const f32x4*>(px + (size_t)r * H_DIM);
        const f32x4 v1 = *reinterpret_cast<const f32x4*>(px + (size_t)(r + WAVES) * H_DIM);
        float sn0, cs0, sn1, cs1;
        __sincosf(wfreq * (float)(t_base + r), &sn0, &cs0);
        __sincosf(wfreq * (float)(t_base + r + WAVES), &sn1, &cs1);
        s0v += v0 + v1;
        c1v += v0 * cs0 + v1 * cs1;
        s1v += v0 * sn0 + v1 * sn1;
    }

    __shared__ float red[WAVES][3 * H_DIM];   // 48 KB
#pragma unroll
    for (int j = 0; j < 4; ++j) {
        red[wave][0 * H_DIM + h0 + j] = s0v[j];
        red[wave][1 * H_DIM + h0 + j] = c1v[j];
        red[wave][2 * H_DIM + h0 + j] = s1v[j];
    }
    __syncthreads();
    if (tid < 3 * H_DIM) {
        float acc = 0.f;
#pragma unroll
        for (int w = 0; w < WAVES; ++w) acc += red[w][tid];
        ws[(size_t)blk * (3 * H_DIM) + tid] = acc;   // quarter-partial for (b,q)
    }

    cg::this_grid().sync();

    // ---- Phase 2 (redundant per block): combine 4 quarter-partials of b ----
    f32x4 S0 = {0.f, 0.f, 0.f, 0.f};
    f32x4 C1 = {0.f, 0.f, 0.f, 0.f};
    f32x4 S1 = {0.f, 0.f, 0.f, 0.f};
#pragma unroll
    for (int k = 0; k < 4; ++k) {
        const float* p = ws + (size_t)((blk & ~3) + k) * (3 * H_DIM);
        S0 += *reinterpret_cast<const f32x4*>(p + h0);
        C1 += *reinterpret_cast<const f32x4*>(p + H_DIM + h0);
        S1 += *reinterpret_cast<const f32x4*>(p + 2 * H_DIM + h0);
    }

    const f32x4 sb = *reinterpret_cast<const f32x4*>(sqrt_beta + h0);
    const f32x4 Wv = *reinterpret_cast<const f32x4*>(lnw + h0);
    const f32x4 Bv = *reinterpret_cast<const f32x4*>(lnb + h0);
    const f32x4 b2 = sb * sb;
    const f32x4 CA = b2 + 1.f;   // coefficient on x
    const f32x4 CB = 1.f - b2;   // coefficient on low_pass
    const float invS = 1.f / (float)S_LEN;

    // ---- Phase 3: reconstruct + residual + LayerNorm over the same rows ----
    float* __restrict__ po = out + ((size_t)b * S_LEN + t_base) * H_DIM + h0;
    for (int r = wave; r < ROWS_PER_BLK; r += WAVES) {
        float sn, cs;
        __sincosf(wfreq * (float)(t_base + r), &sn, &cs);
        const f32x4 v = *reinterpret_cast<const f32x4*>(px + (size_t)r * H_DIM);
        const f32x4 lp = (S0 + (C1 * cs + S1 * sn) * 2.f) * invS;
        const f32x4 y = CB * lp + CA * v;

        float sum = y.x + y.y + y.z + y.w;
        float sumsq = y.x * y.x + y.y * y.y + y.z * y.z + y.w * y.w;
#pragma unroll
        for (int m = 1; m < 64; m <<= 1) {
            sum += __shfl_xor(sum, m, 64);
            sumsq += __shfl_xor(sumsq, m, 64);
        }
        const float mean = sum * (1.f / (float)H_DIM);
        const float var = sumsq * (1.f / (float)H_DIM) - mean * mean;
        const float rstd = rsqrtf(var + 1e-5f);

        f32x4 o = (y - mean) * rstd * Wv + Bv;
        __builtin_nontemporal_store(o, reinterpret_cast<f32x4*>(po + (size_t)r * H_DIM));
    }
}

extern "C" void kernel_launch(void* const* d_in, const int* in_sizes, int n_in,
                              void* d_out, int out_size, void* d_ws, size_t ws_size,
                              hipStream_t stream) {
    const float* x  = (const float*)d_in[0];
    const float* sb = (const float*)d_in[1];
    const float* w  = (const float*)d_in[2];
    const float* bi = (const float*)d_in[3];
    float* out = (float*)d_out;
    float* ws = (float*)d_ws;   // needs 256 * 768 * 4 B = 768 KB

    void* args[] = {(void*)&x, (void*)&sb, (void*)&w, (void*)&bi,
                    (void*)&out, (void*)&ws};
    hipLaunchCooperativeKernel((const void*)k_fused, dim3(NBLK), dim3(NTHR),
                               args, 0, stream);
}